// Round 10
// baseline (104.350 us; speedup 1.0000x reference)
//
#include <hip/hip_runtime.h>
#include <hip/hip_bf16.h>
#include <math.h>

#define BATCH 4096
#define NROW  8192
#define DIM   256

// zb holds bf16( sqrt(2*log2e) * z_hat ), so MFMA acc = 2*log2(e)*sim and
// exp(2*sim) == exp2(acc) — one v_exp_f32 per element, no mul.
#define SCALE_IN 1.69864360f              /* sqrt(2*1.4426950408889634) */
#define LN2      0.69314718055994531f     /* converts acc-units back to 2*sim */

typedef __attribute__((ext_vector_type(8))) short  short8;   // 8 bf16 / 4 VGPRs
typedef __attribute__((ext_vector_type(4))) float  floatx4;  // MFMA C/D

// ---------------------------------------------------------------------------
// ws layout:
//   zb     @ 0     : ushort[8192][256]  (4 MiB)  scaled-normalized bf16
//   part2  @ 4 MiB : float[64][8192]    (2 MiB)  per-diagonal-slice partial
//                    sums — block (r,c), s=c-r, writes rows to slice 2s and
//                    cols to slice 2s+1. Unique writer per slot => PLAIN
//                    STORES, no atomics (R5's atomic finale wrote 23.9 MB
//                    through to HBM — the ~12-15 us that ate the symmetry
//                    savings).
//   bpart  @ 6 MiB : float[2048]        per-block loss partials
// Fixed harness tax ~60 us/replay (256 MiB ws poison-fill ~43 us inside the
// timed window + input restore + dispatch gaps) — not addressable.
// ---------------------------------------------------------------------------

// Wave-per-row: load fp32 row, L2-normalize, scale, write bf16.
// Also zeroes part2 (one float per thread: 2048 blocks x 256 = 512K slots).
__global__ __launch_bounds__(256) void k_prep(const float* __restrict__ z1,
                                              const float* __restrict__ z2,
                                              ushort* __restrict__ zb,
                                              float* __restrict__ part2) {
  part2[(size_t)blockIdx.x * 256 + threadIdx.x] = 0.f;

  int row  = blockIdx.x * 4 + (threadIdx.x >> 6);
  int lane = threadIdx.x & 63;
  const float4* src = (row < BATCH) ? (const float4*)(z1 + (size_t)row * DIM)
                                    : (const float4*)(z2 + (size_t)(row - BATCH) * DIM);
  float4 v = src[lane];
  float ss = v.x * v.x + v.y * v.y + v.z * v.z + v.w * v.w;
#pragma unroll
  for (int off = 1; off < 64; off <<= 1) ss += __shfl_xor(ss, off, 64);
  float s = SCALE_IN / fmaxf(sqrtf(ss), 1e-12f);
  __hip_bfloat16 h0 = __float2bfloat16(v.x * s), h1 = __float2bfloat16(v.y * s);
  __hip_bfloat16 h2 = __float2bfloat16(v.z * s), h3 = __float2bfloat16(v.w * s);
  ushort4 hb = {*(ushort*)&h0, *(ushort*)&h1, *(ushort*)&h2, *(ushort*)&h3};
  ((ushort4*)(zb + (size_t)row * DIM))[lane] = hb;
}

// ---------------------------------------------------------------------------
// Symmetric tile kernel, NO ATOMICS. 528 blocks = upper triangle (r<=c) of
// the 32x32 grid of 256x256 sim tiles; 256 threads / 4 waves; wave owns 64
// rows (Af[4][8] = 128 VGPR pinned, (256,2) budget — no remat/spill, per R3/
// R6 lessons). B staged via LDS uint4 (R5 structure — proven lowest per-work
// cost). Off-diag tiles accumulate col sums (symmetry) in per-wave LDS scol.
// Finale: plain stores to the block's private slices part2[2s]/part2[2s+1].
// MFMA 16x16x32_bf16: A[m=lane&15][k=quad*8+j]; B[k][n=lane&15];
//                     C/D row=quad*4+reg, col=lane&15.
// ---------------------------------------------------------------------------
__global__ __launch_bounds__(256, 2) void k_simsum(const ushort* __restrict__ zb,
                                                   float* __restrict__ part2) {
  __shared__ __align__(16) ushort Bt[64 * 264];   // 33792 B
  __shared__ float scol[4][256];                  // 4096 B

  // upper-triangle decode on the 32-grid: S(r) = r*(65-r)/2 blocks before row r
  int b = blockIdx.x;
  int r = (int)((65.0f - sqrtf(65.0f * 65.0f - 8.0f * (float)b)) * 0.5f);
  r = (r > 31) ? 31 : ((r < 0) ? 0 : r);
  while ((r + 1) * (65 - (r + 1)) / 2 <= b) r++;
  while (r * (65 - r) / 2 > b) r--;
  int c = r + (b - r * (65 - r) / 2);
  const int  s    = c - r;               // diagonal slice 0..31
  const bool diag = (s == 0);

  const int tid  = threadIdx.x;
  const int w    = tid >> 6;
  const int lane = tid & 63;
  const int quad = lane >> 4;
  const int l16  = lane & 15;
  const int rowbase = r * 256 + w * 64;
  const int cbase   = c * 256;

  {
    float* sf = (float*)scol;
    sf[tid] = 0.f; sf[tid + 256] = 0.f; sf[tid + 512] = 0.f; sf[tid + 768] = 0.f;
  }

  // Pin A fragments: 4 rowblocks x 8 k-steps = 128 VGPRs
  short8 Af[4][8];
#pragma unroll
  for (int rb = 0; rb < 4; rb++) {
    const ushort* p = zb + (size_t)(rowbase + rb * 16 + l16) * DIM + quad * 8;
#pragma unroll
    for (int k = 0; k < 8; k++) Af[rb][k] = *(const short8*)(p + k * 32);
  }

  float rsum[4][4];
#pragma unroll
  for (int rb = 0; rb < 4; rb++)
#pragma unroll
    for (int rr = 0; rr < 4; rr++) rsum[rb][rr] = 0.f;

#pragma unroll 1
  for (int ct = 0; ct < 4; ct++) {
    const int c0 = cbase + ct * 64;
    __syncthreads();
    {
      const uint4* src = (const uint4*)(zb + (size_t)c0 * DIM);
#pragma unroll
      for (int i = 0; i < 8; i++) {
        int idx = tid + i * 256;
        int rr = idx >> 5, cc = idx & 31;
        *(uint4*)(&Bt[rr * 264 + cc * 8]) = src[rr * 32 + cc];
      }
    }
    __syncthreads();

#pragma unroll
    for (int cs = 0; cs < 4; cs++) {
      const ushort* bp = &Bt[(cs * 16 + l16) * 264 + quad * 8];
      floatx4 acc[4];
#pragma unroll
      for (int rb = 0; rb < 4; rb++) acc[rb] = (floatx4){0.f, 0.f, 0.f, 0.f};
#pragma unroll
      for (int k = 0; k < 8; k++) {
        short8 Bf = *(const short8*)(bp + k * 32);
#pragma unroll
        for (int rb = 0; rb < 4; rb++)
          acc[rb] = __builtin_amdgcn_mfma_f32_16x16x32_bf16(Af[rb][k], Bf, acc[rb], 0, 0, 0);
      }
      float ca = 0.f;
#pragma unroll
      for (int rb = 0; rb < 4; rb++)
#pragma unroll
        for (int rr = 0; rr < 4; rr++) {
          float e = __builtin_amdgcn_exp2f(acc[rb][rr]);
          rsum[rb][rr] += e;
          ca += e;
        }
      if (!diag) {
        ca += __shfl_xor(ca, 16, 64);
        ca += __shfl_xor(ca, 32, 64);
        if (quad == 0)
          scol[w][ct * 64 + cs * 16 + l16] += ca;   // 16 lanes, 16 banks
      }
    }
  }

  // Row sums -> private slice 2s: plain stores (unique writer per slot).
  float* rowslice = part2 + (size_t)(2 * s) * NROW;
#pragma unroll
  for (int rb = 0; rb < 4; rb++)
#pragma unroll
    for (int rr = 0; rr < 4; rr++) {
      float v = rsum[rb][rr];
#pragma unroll
      for (int off = 1; off < 16; off <<= 1) v += __shfl_xor(v, off, 64);
      if (l16 == 0)
        rowslice[rowbase + rb * 16 + quad * 4 + rr] = v;
    }

  if (!diag) {
    __syncthreads();
    float v = scol[0][tid] + scol[1][tid] + scol[2][tid] + scol[3][tid];
    part2[(size_t)(2 * s + 1) * NROW + cbase + tid] = v;   // coalesced store
  }
}

// ---------------------------------------------------------------------------
// Wave-per-row loss term. 2048 blocks x 256 threads (4 rows/block).
// The 64 lanes reduce the 64 partial slices (one load each) alongside the
// pair-dot and self-dot shfl chains.
//   neg_j = sum_s part2[s][j] - exp2(selfdot_acc_j)
//   t_j   = log(neg_j) - dp_acc_j * ln2      (dp_acc = 2*log2e*sim_pair)
// ---------------------------------------------------------------------------
__global__ __launch_bounds__(256) void k_rowterm(const ushort* __restrict__ zb,
                                                 const float* __restrict__ part2,
                                                 float* __restrict__ bpart) {
  int j    = blockIdx.x * 4 + (threadIdx.x >> 6);
  int lane = threadIdx.x & 63;
  int pj   = (j + BATCH) & (NROW - 1);
  ushort4 ua = ((const ushort4*)(zb + (size_t)j  * DIM))[lane];
  ushort4 ub = ((const ushort4*)(zb + (size_t)pj * DIM))[lane];
  float ng = part2[(size_t)lane * NROW + j];
  uint t;
  float ax, ay, az, aw, bx, by, bz, bw;
  t = (uint)ua.x << 16; ax = *(float*)&t;  t = (uint)ua.y << 16; ay = *(float*)&t;
  t = (uint)ua.z << 16; az = *(float*)&t;  t = (uint)ua.w << 16; aw = *(float*)&t;
  t = (uint)ub.x << 16; bx = *(float*)&t;  t = (uint)ub.y << 16; by = *(float*)&t;
  t = (uint)ub.z << 16; bz = *(float*)&t;  t = (uint)ub.w << 16; bw = *(float*)&t;
  float dp = ax * bx + ay * by + az * bz + aw * bw;
  float sd = ax * ax + ay * ay + az * az + aw * aw;
#pragma unroll
  for (int off = 1; off < 64; off <<= 1) {
    dp += __shfl_xor(dp, off, 64);
    sd += __shfl_xor(sd, off, 64);
    ng += __shfl_xor(ng, off, 64);
  }
  __shared__ float sred[4];
  if (lane == 0) {
    float neg = ng - __builtin_amdgcn_exp2f(sd);
    sred[threadIdx.x >> 6] = logf(neg) - dp * LN2;
  }
  __syncthreads();
  if (threadIdx.x == 0)
    bpart[blockIdx.x] = sred[0] + sred[1] + sred[2] + sred[3];
}

__global__ void k_final(const float* __restrict__ bpart, float* __restrict__ out) {
  int t = threadIdx.x;  // 256 threads
  float v = 0.f;
#pragma unroll
  for (int i = 0; i < 8; i++) v += bpart[t + i * 256];
  int lane = t & 63;
#pragma unroll
  for (int off = 1; off < 64; off <<= 1) v += __shfl_xor(v, off, 64);
  __shared__ float sred[4];
  if (lane == 0) sred[t >> 6] = v;
  __syncthreads();
  if (t == 0) out[0] = (sred[0] + sred[1] + sred[2] + sred[3]) / (float)NROW;
}

extern "C" void kernel_launch(void* const* d_in, const int* in_sizes, int n_in,
                              void* d_out, int out_size, void* d_ws, size_t ws_size,
                              hipStream_t stream) {
  const float* z1 = (const float*)d_in[0];
  const float* z2 = (const float*)d_in[1];
  float* out = (float*)d_out;

  char* ws = (char*)d_ws;
  ushort* zb    = (ushort*)ws;                                   // 4 MiB
  float*  part2 = (float*)(ws + (size_t)4 * 1024 * 1024);        // 2 MiB
  float*  bpart = (float*)(ws + (size_t)6 * 1024 * 1024);

  k_prep<<<NROW / 4, 256, 0, stream>>>(z1, z2, zb, part2);
  k_simsum<<<528, 256, 0, stream>>>(zb, part2);
  k_rowterm<<<NROW / 4, 256, 0, stream>>>(zb, part2, bpart);
  k_final<<<1, 256, 0, stream>>>(bpart, out);
}